// Round 2
// baseline (235.197 us; speedup 1.0000x reference)
//
#include <hip/hip_runtime.h>
#include <hip/hip_bf16.h>

#define B_  16
#define C_  256
#define H_  48
#define W_  64
#define ND  21           // displacements per axis
#define HW  (H_ * W_)
#define CHW (C_ * H_ * W_)

typedef __attribute__((ext_vector_type(8))) short bf16x8;
typedef __attribute__((ext_vector_type(4))) float f32x4;

__device__ __forceinline__ unsigned int bf16rtne(float f) {
  unsigned int u = __builtin_bit_cast(unsigned int, f);
  return (u + 0x7fffu + ((u >> 16) & 1u)) >> 16;
}

// ---------------------------------------------------------------------------
// Kernel 1 (unchanged): fp32 NCHW -> bf16 FRAGMENT-MAJOR layout, per (b,y) row:
//   granule G = ks*256 + t16*64 + quad*16 + l15   (16B granules)
//   content  = bf16 src[x = t16*16+l15][k = ks*32+quad*8 .. +8)
// ---------------------------------------------------------------------------
__global__ __launch_bounds__(256) void transpose_cvt(
    const float* __restrict__ in1, const float* __restrict__ in2,
    unsigned short* __restrict__ o1, unsigned short* __restrict__ o2) {
  __shared__ unsigned short T[256 * 66];   // [c][x], stride 66 (odd word stride)

  int blk = blockIdx.x;
  const float* in = in1;
  unsigned short* op = o1;
  if (blk >= B_ * H_) { blk -= B_ * H_; in = in2; op = o2; }
  int y = blk % H_;
  int b = blk / H_;
  int t = threadIdx.x;

  // ---- phase 1: global fp32 -> bf16 -> LDS[c][x] ----
  int u  = t & 15;          // x-quad: x = 4u..4u+3
  int cb = t >> 4;          // c base 0..15, c = cb + 16r
  const float* src = in + (long)b * CHW + y * W_ + u * 4;
#pragma unroll
  for (int r = 0; r < 16; r++) {
    int c = cb + 16 * r;
    float4 v = *(const float4*)(src + (long)c * HW);
    unsigned int p0 = bf16rtne(v.x) | (bf16rtne(v.y) << 16);
    unsigned int p1 = bf16rtne(v.z) | (bf16rtne(v.w) << 16);
    unsigned int* Tw = (unsigned int*)(T + c * 66 + u * 4);
    Tw[0] = p0;
    Tw[1] = p1;
  }
  __syncthreads();

  // ---- phase 2: LDS gather -> fragment-major 16B stores ----
  int x   = t >> 2;         // pixel 0..63
  int cq  = t & 3;
  int t16 = x >> 4, xl = x & 15;
  unsigned short* orow = op + (long)(b * H_ + y) * (W_ * C_);
#pragma unroll
  for (int g = 0; g < 8; g++) {
    int gg = (g + cq) & 7;              // bank-spread rotation
    int kg = cq * 8 + gg;               // k-granule 0..31
    int c0 = kg * 8;                    // first channel of this granule
    unsigned int wv[4];
#pragma unroll
    for (int k2 = 0; k2 < 4; k2++) {
      unsigned int lo = T[(c0 + 2 * k2) * 66 + x];
      unsigned int hi = T[(c0 + 2 * k2 + 1) * 66 + x];
      wv[k2] = lo | (hi << 16);
    }
    int ks = kg >> 2, qd = kg & 3;
    int G = ks * 256 + t16 * 64 + qd * 16 + xl;
    *(uint4*)(orow + (long)G * 8) = *(uint4*)wv;
  }
}

// ---------------------------------------------------------------------------
// async global -> LDS, 16B per lane (wave-uniform LDS base + lane*16)
// ---------------------------------------------------------------------------
__device__ __forceinline__ void gl_lds16(const void* g, void* l) {
  __builtin_amdgcn_global_load_lds(
      (const __attribute__((address_space(1))) void*)g,
      (__attribute__((address_space(3))) void*)l, 16, 0, 0);
}

// ---------------------------------------------------------------------------
// Kernel 2: correlation v7 — ONE barrier per dyi.
//   v6 had 3 full-drain __syncthreads per dyi; the barrier immediately after
//   the coalesced store also drained the store-acks cold. v7:
//   - slab double-buffered [2][21*65]: scatter(d)->slab[sp], store of
//     slab[sp^1] (= dyi d-1) moved BEFORE compute(d) so store-acks drain
//     under the MFMA phase.
//   - iteration = stage(d+1) | store(d-1)+rezero | compute(d) | scatter(d)
//     | ONE __syncthreads. That single barrier covers all 4 cross-wave
//     hazards: stage vmcnt drain, scatter->store visibility, rezero-before-
//     scatter (parity alternates), Bb[cur] reads-before-restage.
// LDS = 64KB Bb + 10.9KB slab = 76.5KB -> 2 blocks/CU.
// ---------------------------------------------------------------------------
__global__ __launch_bounds__(256, 2) void corr_kernel(
    const unsigned short* __restrict__ A2, const unsigned short* __restrict__ B2,
    float* __restrict__ out) {
  __shared__ unsigned short Bb[2][16384];   // 2 x 32KB B-row double buffer
  __shared__ float slab[2][ND * 65];        // [buf][dxi][x], pad 65

  int bid = blockIdx.x;
  int blk = (bid & 7) * 96 + (bid >> 3);    // XCD swizzle, bijective (768=8*96)
  int y    = blk % H_;
  int b    = blk / H_;
  int t    = threadIdx.x;
  int lane = t & 63;
  int w    = t >> 6;
  int l15  = lane & 15;
  int quad = lane >> 4;
  int mh   = w & 1;
  int nh   = w >> 1;

  // contiguous valid-dyi range: y2 = y + 2*d - 20 in [0,H)
  int dlo = (y < 20) ? ((21 - y) >> 1) : 0;
  int dhi = (67 - y) >> 1; if (dhi > 20) dhi = 20;

  const unsigned short* browbase = B2 + (long)(b * H_) * (W_ * C_);

  // ---- prologue: issue first B-row stage ASAP ----
  {
    int y2 = y + 2 * dlo - 20;
    const unsigned short* src = browbase + (long)y2 * (W_ * C_) + lane * 8;
#pragma unroll
    for (int j = 0; j < 8; j++) {
      int c = w * 8 + j;                    // each wave stages 8 x 1KB chunks
      gl_lds16(src + c * 512, &Bb[0][c * 512]);
    }
  }

  // ---- A fragments: registers, once per block ----
  const unsigned short* rowA = A2 + (long)(b * H_ + y) * (W_ * C_);
  bf16x8 afrag[2][8];
#pragma unroll
  for (int mtl = 0; mtl < 2; mtl++) {
    int mtg = mh * 2 + mtl;
#pragma unroll
    for (int ks = 0; ks < 8; ks++)
      afrag[mtl][ks] = *(const bf16x8*)(rowA + ks * 2048 + mtg * 512 + lane * 8);
  }

  // ---- per-lane slab-scatter offsets (dyi-invariant): dxi*65 + xx, or -1 ----
  int soff[2][2][4];
#pragma unroll
  for (int mtl = 0; mtl < 2; mtl++)
#pragma unroll
    for (int ntl = 0; ntl < 2; ntl++)
#pragma unroll
      for (int r = 0; r < 4; r++) {
        int xx = (mh * 2 + mtl) * 16 + quad * 4 + r;
        int xp = (nh * 2 + ntl) * 16 + l15;
        int dx = xp - xx;
        soff[mtl][ntl][r] =
            (dx >= -20 && dx <= 20 && !(dx & 1)) ? (((dx + 20) >> 1) * 65 + xx) : -1;
      }

  // tile-pair liveness (wave-uniform): |16*(ntg-mtg)| <= 35
  bool live[2][2];
#pragma unroll
  for (int mtl = 0; mtl < 2; mtl++)
#pragma unroll
    for (int ntl = 0; ntl < 2; ntl++) {
      int diff = (nh * 2 + ntl) - (mh * 2 + mtl);
      live[mtl][ntl] = (diff >= -2 && diff <= 2);
    }

  float* ob = out + (long)b * (ND * ND * HW) + y * W_;

  // ---- zero planes for out-of-range dyi (coalesced; overlaps first stage) ----
  for (int d = 0; d < dlo; d++) {
    float* od = ob + (long)d * (ND * HW);
    for (int i = t; i < ND * W_; i += 256) od[(i >> 6) * HW + (i & 63)] = 0.0f;
  }
  for (int d = dhi + 1; d < ND; d++) {
    float* od = ob + (long)d * (ND * HW);
    for (int i = t; i < ND * W_; i += 256) od[(i >> 6) * HW + (i & 63)] = 0.0f;
  }

  // ---- zero-init both slabs ----
  for (int i = t; i < 2 * ND * 65; i += 256) slab[0][i] = 0.0f;

  __syncthreads();   // drains prologue stage (vmcnt) + slab init

  int cur = 0, sp = 0;
  for (int d = dlo; d <= dhi; d++) {
    // ---- (1) issue next dyi's B-row stage into the other buffer ----
    if (d < dhi) {
      int y2n = y + 2 * (d + 1) - 20;
      const unsigned short* src = browbase + (long)y2n * (W_ * C_) + lane * 8;
#pragma unroll
      for (int j = 0; j < 8; j++) {
        int c = w * 8 + j;
        gl_lds16(src + c * 512, &Bb[cur ^ 1][c * 512]);
      }
    }

    // ---- (2) store previous dyi's slab (coalesced) + rezero it ----
    //      store-acks drain under the compute phase below, not at a barrier
    if (d > dlo) {
      float* odp = ob + (long)(d - 1) * (ND * HW);
      float* sl = slab[sp ^ 1];
      for (int i = t; i < ND * W_; i += 256) {
        int dxi = i >> 6, x = i & 63;
        odp[dxi * HW + x] = sl[dxi * 65 + x];
        sl[dxi * 65 + x] = 0.0f;
      }
    }

    // ---- (3) compute from Bb[cur]: conflict-free ds_read_b128 + MFMA ----
    const unsigned short* lb = &Bb[cur][0];
    f32x4 acc[2][2];
#pragma unroll
    for (int mtl = 0; mtl < 2; mtl++)
#pragma unroll
      for (int ntl = 0; ntl < 2; ntl++) acc[mtl][ntl] = (f32x4){0.f, 0.f, 0.f, 0.f};

#pragma unroll
    for (int ks = 0; ks < 8; ks++) {
      bf16x8 b0 = *(const bf16x8*)(lb + ks * 2048 + (nh * 2 + 0) * 512 + lane * 8);
      bf16x8 b1 = *(const bf16x8*)(lb + ks * 2048 + (nh * 2 + 1) * 512 + lane * 8);
#pragma unroll
      for (int mtl = 0; mtl < 2; mtl++) {
        if (live[mtl][0])
          acc[mtl][0] = __builtin_amdgcn_mfma_f32_16x16x32_bf16(afrag[mtl][ks], b0,
                                                                acc[mtl][0], 0, 0, 0);
        if (live[mtl][1])
          acc[mtl][1] = __builtin_amdgcn_mfma_f32_16x16x32_bf16(afrag[mtl][ks], b1,
                                                                acc[mtl][1], 0, 0, 0);
      }
    }

    // ---- (4) band-extract scatter into slab[sp] ----
#pragma unroll
    for (int mtl = 0; mtl < 2; mtl++)
#pragma unroll
      for (int ntl = 0; ntl < 2; ntl++)
#pragma unroll
        for (int r = 0; r < 4; r++) {
          int so = soff[mtl][ntl][r];
          if (so >= 0) slab[sp][so] = acc[mtl][ntl][r] * (1.0f / 256.0f);
        }

    // ---- (5) THE barrier: stage drained, scatter visible, rezero ordered ----
    __syncthreads();
    cur ^= 1;
    sp ^= 1;
  }

  // ---- epilogue: store last dyi's slab ----
  {
    float* odp = ob + (long)dhi * (ND * HW);
    float* sl = slab[sp ^ 1];
    for (int i = t; i < ND * W_; i += 256) {
      int dxi = i >> 6, x = i & 63;
      odp[dxi * HW + x] = sl[dxi * 65 + x];
    }
  }
}

// ---------------------------------------------------------------------------
extern "C" void kernel_launch(void* const* d_in, const int* in_sizes, int n_in,
                              void* d_out, int out_size, void* d_ws, size_t ws_size,
                              hipStream_t stream) {
  (void)in_sizes; (void)n_in; (void)out_size; (void)ws_size;
  const float* in1 = (const float*)d_in[0];
  const float* in2 = (const float*)d_in[1];
  float* out = (float*)d_out;

  unsigned short* o1 = (unsigned short*)d_ws;                    // bf16 frag-major
  unsigned short* o2 = o1 + (size_t)B_ * H_ * W_ * C_;           // bf16 frag-major

  transpose_cvt<<<2 * B_ * H_, 256, 0, stream>>>(in1, in2, o1, o2);
  corr_kernel<<<B_ * H_, 256, 0, stream>>>(o1, o2, out);
}

// Round 3
// 210.383 us; speedup vs baseline: 1.1179x; 1.1179x over previous
//
#include <hip/hip_runtime.h>
#include <hip/hip_bf16.h>

#define B_  16
#define C_  256
#define H_  48
#define W_  64
#define ND  21           // displacements per axis
#define HW  (H_ * W_)
#define CHW (C_ * H_ * W_)

typedef __attribute__((ext_vector_type(8))) short bf16x8;
typedef __attribute__((ext_vector_type(4))) float f32x4;

__device__ __forceinline__ unsigned int bf16rtne(float f) {
  unsigned int u = __builtin_bit_cast(unsigned int, f);
  return (u + 0x7fffu + ((u >> 16) & 1u)) >> 16;
}

// ---------------------------------------------------------------------------
// Kernel 1 (unchanged): fp32 NCHW -> bf16 FRAGMENT-MAJOR layout, per (b,y) row:
//   granule G = ks*256 + t16*64 + quad*16 + l15   (16B granules)
//   content  = bf16 src[x = t16*16+l15][k = ks*32+quad*8 .. +8)
// ---------------------------------------------------------------------------
__global__ __launch_bounds__(256) void transpose_cvt(
    const float* __restrict__ in1, const float* __restrict__ in2,
    unsigned short* __restrict__ o1, unsigned short* __restrict__ o2) {
  __shared__ unsigned short T[256 * 66];   // [c][x], stride 66 (odd word stride)

  int blk = blockIdx.x;
  const float* in = in1;
  unsigned short* op = o1;
  if (blk >= B_ * H_) { blk -= B_ * H_; in = in2; op = o2; }
  int y = blk % H_;
  int b = blk / H_;
  int t = threadIdx.x;

  // ---- phase 1: global fp32 -> bf16 -> LDS[c][x] ----
  int u  = t & 15;          // x-quad: x = 4u..4u+3
  int cb = t >> 4;          // c base 0..15, c = cb + 16r
  const float* src = in + (long)b * CHW + y * W_ + u * 4;
#pragma unroll
  for (int r = 0; r < 16; r++) {
    int c = cb + 16 * r;
    float4 v = *(const float4*)(src + (long)c * HW);
    unsigned int p0 = bf16rtne(v.x) | (bf16rtne(v.y) << 16);
    unsigned int p1 = bf16rtne(v.z) | (bf16rtne(v.w) << 16);
    unsigned int* Tw = (unsigned int*)(T + c * 66 + u * 4);
    Tw[0] = p0;
    Tw[1] = p1;
  }
  __syncthreads();

  // ---- phase 2: LDS gather -> fragment-major 16B stores ----
  int x   = t >> 2;         // pixel 0..63
  int cq  = t & 3;
  int t16 = x >> 4, xl = x & 15;
  unsigned short* orow = op + (long)(b * H_ + y) * (W_ * C_);
#pragma unroll
  for (int g = 0; g < 8; g++) {
    int gg = (g + cq) & 7;              // bank-spread rotation
    int kg = cq * 8 + gg;               // k-granule 0..31
    int c0 = kg * 8;                    // first channel of this granule
    unsigned int wv[4];
#pragma unroll
    for (int k2 = 0; k2 < 4; k2++) {
      unsigned int lo = T[(c0 + 2 * k2) * 66 + x];
      unsigned int hi = T[(c0 + 2 * k2 + 1) * 66 + x];
      wv[k2] = lo | (hi << 16);
    }
    int ks = kg >> 2, qd = kg & 3;
    int G = ks * 256 + t16 * 64 + qd * 16 + xl;
    *(uint4*)(orow + (long)G * 8) = *(uint4*)wv;
  }
}

// ---------------------------------------------------------------------------
// Kernel 2: correlation v8 — B direct from L2 to registers (NO B-LDS, no
// stage, no vmcnt-laden barriers). The v6/v7 LDS double-buffer cost 64KB LDS
// (-> 2 blocks/CU) to hide a latency it never hid: the barrier's vmcnt(0)
// drained a 32KB stage issued in the SAME iteration (~7.5k cyc/iter slots).
// v8:
//   - XCD swizzle keeps B rows L2-resident (R1-proven: FETCH 240->28 MB);
//     ks-pipelined register loads stream from L2, consumed by MFMA via
//     data-dependence -> nothing pending at barriers except old store-acks.
//   - LDS = 2 output slabs only (10.9 KB) -> __launch_bounds__(256,3):
//     3 blocks/CU, 768 = 256x3 grid fully resident, ZERO dispatch tail.
//     12 waves/CU x ~3KB loads in flight saturates the per-CU L2 share
//     (~56 B/cyc) -> BW-streaming regime, not latency-bound.
//   - iteration: store slab(d-1) | compute(d) | scatter(d) | ONE barrier.
// ---------------------------------------------------------------------------
__global__ __launch_bounds__(256, 3) void corr_kernel(
    const unsigned short* __restrict__ A2, const unsigned short* __restrict__ B2,
    float* __restrict__ out) {
  __shared__ float slab[2][ND * 65];        // [buf][dxi][x], pad 65

  int bid = blockIdx.x;
  int blk = (bid & 7) * 96 + (bid >> 3);    // XCD swizzle, bijective (768=8*96)
  int y    = blk % H_;
  int b    = blk / H_;
  int t    = threadIdx.x;
  int lane = t & 63;
  int w    = t >> 6;
  int l15  = lane & 15;
  int quad = lane >> 4;
  int mh   = w & 1;
  int nh   = w >> 1;

  // contiguous valid-dyi range: y2 = y + 2*d - 20 in [0,H)
  int dlo = (y < 20) ? ((21 - y) >> 1) : 0;
  int dhi = (67 - y) >> 1; if (dhi > 20) dhi = 20;

  // ---- A fragments: registers, once per block (1KB contiguous loads) ----
  const unsigned short* rowA = A2 + (long)(b * H_ + y) * (W_ * C_);
  bf16x8 afrag[2][8];
#pragma unroll
  for (int mtl = 0; mtl < 2; mtl++) {
    int mtg = mh * 2 + mtl;
#pragma unroll
    for (int ks = 0; ks < 8; ks++)
      afrag[mtl][ks] = *(const bf16x8*)(rowA + ks * 2048 + mtg * 512 + lane * 8);
  }

  // ---- per-lane slab-scatter offsets (dyi-invariant): dxi*65 + xx, or -1 ----
  int soff[2][2][4];
#pragma unroll
  for (int mtl = 0; mtl < 2; mtl++)
#pragma unroll
    for (int ntl = 0; ntl < 2; ntl++)
#pragma unroll
      for (int r = 0; r < 4; r++) {
        int xx = (mh * 2 + mtl) * 16 + quad * 4 + r;
        int xp = (nh * 2 + ntl) * 16 + l15;
        int dx = xp - xx;
        soff[mtl][ntl][r] =
            (dx >= -20 && dx <= 20 && !(dx & 1)) ? (((dx + 20) >> 1) * 65 + xx) : -1;
      }

  // tile-pair liveness (wave-uniform): |16*(ntg-mtg)| <= 35
  bool live[2][2];
#pragma unroll
  for (int mtl = 0; mtl < 2; mtl++)
#pragma unroll
    for (int ntl = 0; ntl < 2; ntl++) {
      int diff = (nh * 2 + ntl) - (mh * 2 + mtl);
      live[mtl][ntl] = (diff >= -2 && diff <= 2);
    }

  float* ob = out + (long)b * (ND * ND * HW) + y * W_;

  // ---- zero planes for out-of-range dyi (coalesced) ----
  for (int d = 0; d < dlo; d++) {
    float* od = ob + (long)d * (ND * HW);
    for (int i = t; i < ND * W_; i += 256) od[(i >> 6) * HW + (i & 63)] = 0.0f;
  }
  for (int d = dhi + 1; d < ND; d++) {
    float* od = ob + (long)d * (ND * HW);
    for (int i = t; i < ND * W_; i += 256) od[(i >> 6) * HW + (i & 63)] = 0.0f;
  }

  // ---- zero-init both slabs (contiguous) ----
  {
    float* s0 = &slab[0][0];
    for (int i = t; i < 2 * ND * 65; i += 256) s0[i] = 0.0f;
  }
  __syncthreads();

  const unsigned short* browbase = B2 + (long)(b * H_) * (W_ * C_);
  int sp = 0;
  for (int d = dlo; d <= dhi; d++) {
    // ---- (1) store previous dyi's slab (coalesced 256B/wave) + rezero ----
    //      store-acks drain under the compute phase, not at a cold barrier
    if (d > dlo) {
      float* odp = ob + (long)(d - 1) * (ND * HW);
      float* sl = slab[sp ^ 1];
      for (int i = t; i < ND * W_; i += 256) {
        int dxi = i >> 6, x = i & 63;
        odp[dxi * HW + x] = sl[dxi * 65 + x];
        sl[dxi * 65 + x] = 0.0f;
      }
    }

    // ---- (2) compute(d): ks-pipelined B stream, L2 -> regs -> MFMA ----
    int y2 = y + 2 * d - 20;
    const unsigned short* rowB = browbase + (long)y2 * (W_ * C_);
    f32x4 acc[2][2];
#pragma unroll
    for (int mtl = 0; mtl < 2; mtl++)
#pragma unroll
      for (int ntl = 0; ntl < 2; ntl++) acc[mtl][ntl] = (f32x4){0.f, 0.f, 0.f, 0.f};

    bf16x8 bc0 = *(const bf16x8*)(rowB + (nh * 2 + 0) * 512 + lane * 8);
    bf16x8 bc1 = *(const bf16x8*)(rowB + (nh * 2 + 1) * 512 + lane * 8);
#pragma unroll
    for (int ks = 0; ks < 8; ks++) {
      int ksn = (ks < 7) ? ks + 1 : 0;               // clamp: no OOB read (L1 hit)
      bf16x8 bn0 = *(const bf16x8*)(rowB + ksn * 2048 + (nh * 2 + 0) * 512 + lane * 8);
      bf16x8 bn1 = *(const bf16x8*)(rowB + ksn * 2048 + (nh * 2 + 1) * 512 + lane * 8);
#pragma unroll
      for (int mtl = 0; mtl < 2; mtl++) {
        if (live[mtl][0])
          acc[mtl][0] = __builtin_amdgcn_mfma_f32_16x16x32_bf16(afrag[mtl][ks], bc0,
                                                                acc[mtl][0], 0, 0, 0);
        if (live[mtl][1])
          acc[mtl][1] = __builtin_amdgcn_mfma_f32_16x16x32_bf16(afrag[mtl][ks], bc1,
                                                                acc[mtl][1], 0, 0, 0);
      }
      bc0 = bn0;
      bc1 = bn1;
    }

    // ---- (3) band-extract scatter into slab[sp] ----
#pragma unroll
    for (int mtl = 0; mtl < 2; mtl++)
#pragma unroll
      for (int ntl = 0; ntl < 2; ntl++)
#pragma unroll
        for (int r = 0; r < 4; r++) {
          int so = soff[mtl][ntl][r];
          if (so >= 0) slab[sp][so] = acc[mtl][ntl][r] * (1.0f / 256.0f);
        }

    // ---- (4) ONE barrier: scatter visible, rezero ordered for next iter ----
    __syncthreads();
    sp ^= 1;
  }

  // ---- epilogue: store last dyi's slab ----
  {
    float* odp = ob + (long)dhi * (ND * HW);
    float* sl = slab[sp ^ 1];
    for (int i = t; i < ND * W_; i += 256) {
      int dxi = i >> 6, x = i & 63;
      odp[dxi * HW + x] = sl[dxi * 65 + x];
    }
  }
}

// ---------------------------------------------------------------------------
extern "C" void kernel_launch(void* const* d_in, const int* in_sizes, int n_in,
                              void* d_out, int out_size, void* d_ws, size_t ws_size,
                              hipStream_t stream) {
  (void)in_sizes; (void)n_in; (void)out_size; (void)ws_size;
  const float* in1 = (const float*)d_in[0];
  const float* in2 = (const float*)d_in[1];
  float* out = (float*)d_out;

  unsigned short* o1 = (unsigned short*)d_ws;                    // bf16 frag-major
  unsigned short* o2 = o1 + (size_t)B_ * H_ * W_ * C_;           // bf16 frag-major

  transpose_cvt<<<2 * B_ * H_, 256, 0, stream>>>(in1, in2, o1, o2);
  corr_kernel<<<B_ * H_, 256, 0, stream>>>(o1, o2, out);
}

// Round 4
// 205.912 us; speedup vs baseline: 1.1422x; 1.0217x over previous
//
#include <hip/hip_runtime.h>
#include <hip/hip_bf16.h>

#define B_  16
#define C_  256
#define H_  48
#define W_  64
#define ND  21           // displacements per axis
#define HW  (H_ * W_)
#define CHW (C_ * H_ * W_)

typedef __attribute__((ext_vector_type(8))) short bf16x8;
typedef __attribute__((ext_vector_type(4))) float f32x4;

__device__ __forceinline__ unsigned int bf16rtne(float f) {
  unsigned int u = __builtin_bit_cast(unsigned int, f);
  return (u + 0x7fffu + ((u >> 16) & 1u)) >> 16;
}

// ---------------------------------------------------------------------------
// Kernel 1 v2: fp32 NCHW -> bf16 FRAGMENT-MAJOR, split into 2 channel-half
// blocks per (input,b,y) row. v1 was latency-bound (VALUBusy 6%, occ 28%,
// 1.9 TB/s): 33.8KB LDS -> ~2 blocks/CU and 16 loads/thread at VGPR 52.
// v2: 128 channels/block -> LDS 16.9KB, 8 loads/thread, launch_bounds(256,8)
// -> up to 8 blocks/CU. Fragment index splits cleanly on ks: kg = ch*16+kgl.
//   granule G = ks*256 + t16*64 + quad*16 + l15  (16B granules)
//   content  = bf16 src[x = t16*16+l15][k = ks*32+quad*8 .. +8)
// grid = 4*B*H = 3072 blocks.
// ---------------------------------------------------------------------------
__global__ __launch_bounds__(256, 8) void transpose_cvt(
    const float* __restrict__ in1, const float* __restrict__ in2,
    unsigned short* __restrict__ o1, unsigned short* __restrict__ o2) {
  __shared__ unsigned short T[128 * 66];   // [cl][x], stride 66 (odd word stride)

  int bid = blockIdx.x;
  int ch  = bid & 1;                       // channel half: c in [ch*128, ch*128+128)
  int blk = bid >> 1;
  const float* in = in1;
  unsigned short* op = o1;
  if (blk >= B_ * H_) { blk -= B_ * H_; in = in2; op = o2; }
  int y = blk % H_;
  int b = blk / H_;
  int t = threadIdx.x;

  // ---- phase 1: global fp32 -> bf16 -> LDS[cl][x] ----
  int u  = t & 15;          // x-quad: x = 4u..4u+3
  int cb = t >> 4;          // local c base 0..15, cl = cb + 16r
  const float* src = in + (long)b * CHW + (long)(ch * 128) * HW + y * W_ + u * 4;
#pragma unroll
  for (int r = 0; r < 8; r++) {
    int cl = cb + 16 * r;
    float4 v = *(const float4*)(src + (long)cl * HW);
    unsigned int p0 = bf16rtne(v.x) | (bf16rtne(v.y) << 16);
    unsigned int p1 = bf16rtne(v.z) | (bf16rtne(v.w) << 16);
    unsigned int* Tw = (unsigned int*)(T + cl * 66 + u * 4);
    Tw[0] = p0;
    Tw[1] = p1;
  }
  __syncthreads();

  // ---- phase 2: LDS gather -> fragment-major 16B stores ----
  int x   = t >> 2;         // pixel 0..63
  int cq  = t & 3;
  int t16 = x >> 4, xl = x & 15;
  unsigned short* orow = op + (long)(b * H_ + y) * (W_ * C_);
#pragma unroll
  for (int g = 0; g < 4; g++) {
    int gg = (g + cq) & 3;              // bank-spread rotation
    int kgl = cq * 4 + gg;              // local k-granule 0..15
    int c0 = kgl * 8;                   // first local channel of this granule
    unsigned int wv[4];
#pragma unroll
    for (int k2 = 0; k2 < 4; k2++) {
      unsigned int lo = T[(c0 + 2 * k2) * 66 + x];
      unsigned int hi = T[(c0 + 2 * k2 + 1) * 66 + x];
      wv[k2] = lo | (hi << 16);
    }
    int kg = ch * 16 + kgl;             // global k-granule 0..31
    int ks = kg >> 2, qd = kg & 3;
    int G = ks * 256 + t16 * 64 + qd * 16 + xl;
    *(uint4*)(orow + (long)G * 8) = *(uint4*)wv;
  }
}

// ---------------------------------------------------------------------------
// Kernel 2: correlation v9 — depth-4-ks B prefetch.
// v8 counters (MfmaUtil 15.8, VALUBusy 23.7, FETCH=A only): compute loop was
// L2-LATENCY-bound — depth-1 ks-pipeline exposed ~170 cyc/ks. v9:
//   - first 4 ks' B loads (8 loads) issued BEFORE the slab-store phase, so
//     the store/rezero work covers their ~200cyc L2 latency;
//   - in-loop prefetch at distance 4 ks (rolling ~40 VGPR of B in flight).
//   - everything else from v8 kept: XCD swizzle (B L2-resident), no B-LDS,
//     double-buffered output slab, ONE cheap barrier per dyi.
// VGPR ~150 < 170 cap -> still 3 blocks/CU, full grid resident.
// ---------------------------------------------------------------------------
__global__ __launch_bounds__(256, 3) void corr_kernel(
    const unsigned short* __restrict__ A2, const unsigned short* __restrict__ B2,
    float* __restrict__ out) {
  __shared__ float slab[2][ND * 65];        // [buf][dxi][x], pad 65

  int bid = blockIdx.x;
  int blk = (bid & 7) * 96 + (bid >> 3);    // XCD swizzle, bijective (768=8*96)
  int y    = blk % H_;
  int b    = blk / H_;
  int t    = threadIdx.x;
  int lane = t & 63;
  int w    = t >> 6;
  int l15  = lane & 15;
  int quad = lane >> 4;
  int mh   = w & 1;
  int nh   = w >> 1;

  // contiguous valid-dyi range: y2 = y + 2*d - 20 in [0,H)
  int dlo = (y < 20) ? ((21 - y) >> 1) : 0;
  int dhi = (67 - y) >> 1; if (dhi > 20) dhi = 20;

  // ---- A fragments: registers, once per block (1KB contiguous loads) ----
  const unsigned short* rowA = A2 + (long)(b * H_ + y) * (W_ * C_);
  bf16x8 afrag[2][8];
#pragma unroll
  for (int mtl = 0; mtl < 2; mtl++) {
    int mtg = mh * 2 + mtl;
#pragma unroll
    for (int ks = 0; ks < 8; ks++)
      afrag[mtl][ks] = *(const bf16x8*)(rowA + ks * 2048 + mtg * 512 + lane * 8);
  }

  // ---- per-lane slab-scatter offsets (dyi-invariant): dxi*65 + xx, or -1 ----
  int soff[2][2][4];
#pragma unroll
  for (int mtl = 0; mtl < 2; mtl++)
#pragma unroll
    for (int ntl = 0; ntl < 2; ntl++)
#pragma unroll
      for (int r = 0; r < 4; r++) {
        int xx = (mh * 2 + mtl) * 16 + quad * 4 + r;
        int xp = (nh * 2 + ntl) * 16 + l15;
        int dx = xp - xx;
        soff[mtl][ntl][r] =
            (dx >= -20 && dx <= 20 && !(dx & 1)) ? (((dx + 20) >> 1) * 65 + xx) : -1;
      }

  // tile-pair liveness (wave-uniform): |16*(ntg-mtg)| <= 35
  bool live[2][2];
#pragma unroll
  for (int mtl = 0; mtl < 2; mtl++)
#pragma unroll
    for (int ntl = 0; ntl < 2; ntl++) {
      int diff = (nh * 2 + ntl) - (mh * 2 + mtl);
      live[mtl][ntl] = (diff >= -2 && diff <= 2);
    }

  float* ob = out + (long)b * (ND * ND * HW) + y * W_;

  // ---- zero planes for out-of-range dyi (coalesced) ----
  for (int d = 0; d < dlo; d++) {
    float* od = ob + (long)d * (ND * HW);
    for (int i = t; i < ND * W_; i += 256) od[(i >> 6) * HW + (i & 63)] = 0.0f;
  }
  for (int d = dhi + 1; d < ND; d++) {
    float* od = ob + (long)d * (ND * HW);
    for (int i = t; i < ND * W_; i += 256) od[(i >> 6) * HW + (i & 63)] = 0.0f;
  }

  // ---- zero-init both slabs (contiguous) ----
  {
    float* s0 = &slab[0][0];
    for (int i = t; i < 2 * ND * 65; i += 256) s0[i] = 0.0f;
  }
  __syncthreads();

  const unsigned short* browbase = B2 + (long)(b * H_) * (W_ * C_);
  int sp = 0;
  for (int d = dlo; d <= dhi; d++) {
    int y2 = y + 2 * d - 20;
    const unsigned short* rowB = browbase + (long)y2 * (W_ * C_);
    const unsigned short* rb0 = rowB + (nh * 2 + 0) * 512 + lane * 8;
    const unsigned short* rb1 = rowB + (nh * 2 + 1) * 512 + lane * 8;

    // ---- (0) issue B loads for ks 0..3 NOW; slab-store below covers latency
    bf16x8 bp[8][2];
#pragma unroll
    for (int ks = 0; ks < 4; ks++) {
      bp[ks][0] = *(const bf16x8*)(rb0 + ks * 2048);
      bp[ks][1] = *(const bf16x8*)(rb1 + ks * 2048);
    }

    // ---- (1) store previous dyi's slab (coalesced 256B/wave) + rezero ----
    if (d > dlo) {
      float* odp = ob + (long)(d - 1) * (ND * HW);
      float* sl = slab[sp ^ 1];
      for (int i = t; i < ND * W_; i += 256) {
        int dxi = i >> 6, x = i & 63;
        odp[dxi * HW + x] = sl[dxi * 65 + x];
        sl[dxi * 65 + x] = 0.0f;
      }
    }

    // ---- (2) MFMA loop, in-loop prefetch at distance 4 ks ----
    f32x4 acc[2][2];
#pragma unroll
    for (int mtl = 0; mtl < 2; mtl++)
#pragma unroll
      for (int ntl = 0; ntl < 2; ntl++) acc[mtl][ntl] = (f32x4){0.f, 0.f, 0.f, 0.f};

#pragma unroll
    for (int ks = 0; ks < 8; ks++) {
      if (ks < 4) {
        bp[ks + 4][0] = *(const bf16x8*)(rb0 + (ks + 4) * 2048);
        bp[ks + 4][1] = *(const bf16x8*)(rb1 + (ks + 4) * 2048);
      }
#pragma unroll
      for (int mtl = 0; mtl < 2; mtl++) {
        if (live[mtl][0])
          acc[mtl][0] = __builtin_amdgcn_mfma_f32_16x16x32_bf16(afrag[mtl][ks], bp[ks][0],
                                                                acc[mtl][0], 0, 0, 0);
        if (live[mtl][1])
          acc[mtl][1] = __builtin_amdgcn_mfma_f32_16x16x32_bf16(afrag[mtl][ks], bp[ks][1],
                                                                acc[mtl][1], 0, 0, 0);
      }
    }

    // ---- (3) band-extract scatter into slab[sp] ----
#pragma unroll
    for (int mtl = 0; mtl < 2; mtl++)
#pragma unroll
      for (int ntl = 0; ntl < 2; ntl++)
#pragma unroll
        for (int r = 0; r < 4; r++) {
          int so = soff[mtl][ntl][r];
          if (so >= 0) slab[sp][so] = acc[mtl][ntl][r] * (1.0f / 256.0f);
        }

    // ---- (4) ONE barrier: scatter visible, rezero ordered for next iter ----
    __syncthreads();
    sp ^= 1;
  }

  // ---- epilogue: store last dyi's slab ----
  {
    float* odp = ob + (long)dhi * (ND * HW);
    float* sl = slab[sp ^ 1];
    for (int i = t; i < ND * W_; i += 256) {
      int dxi = i >> 6, x = i & 63;
      odp[dxi * HW + x] = sl[dxi * 65 + x];
    }
  }
}

// ---------------------------------------------------------------------------
extern "C" void kernel_launch(void* const* d_in, const int* in_sizes, int n_in,
                              void* d_out, int out_size, void* d_ws, size_t ws_size,
                              hipStream_t stream) {
  (void)in_sizes; (void)n_in; (void)out_size; (void)ws_size;
  const float* in1 = (const float*)d_in[0];
  const float* in2 = (const float*)d_in[1];
  float* out = (float*)d_out;

  unsigned short* o1 = (unsigned short*)d_ws;                    // bf16 frag-major
  unsigned short* o2 = o1 + (size_t)B_ * H_ * W_ * C_;           // bf16 frag-major

  transpose_cvt<<<4 * B_ * H_, 256, 0, stream>>>(in1, in2, o1, o2);
  corr_kernel<<<B_ * H_, 256, 0, stream>>>(o1, o2, out);
}